// Round 2
// baseline (223.021 us; speedup 1.0000x reference)
//
#include <hip/hip_runtime.h>
#include <hip/hip_bf16.h>

#define IN_F   4096
#define OUT_F  4096
#define BATCH  64
#define KSPLIT 16
#define KC     (IN_F / KSPLIT)       // 256 -> 8 K-steps of 32
#define COLS_PER_BLOCK 64            // 4 waves * 16 cols

typedef __attribute__((ext_vector_type(8))) short  bf16x8;
typedef __attribute__((ext_vector_type(4))) float  f32x4;

__device__ __forceinline__ float softplus_f(float r) {
    // log(1+e^r) = max(r,0) + log(1+e^-|r|)
    return fmaxf(r, 0.0f) + __logf(1.0f + __expf(-fabsf(r)));
}

__device__ __forceinline__ short bf16_of(float f) {
    // round-to-nearest-even f32 -> bf16, return raw bits
    union { float f; unsigned u; } v; v.f = f;
    unsigned r = v.u + 0x7FFFu + ((v.u >> 16) & 1u);
    return (short)(r >> 16);
}

__device__ __forceinline__ bf16x8 pack8(float w0, float w1, float w2, float w3,
                                        float w4, float w5, float w6, float w7) {
    bf16x8 b;
    b[0] = bf16_of(w0); b[1] = bf16_of(w1); b[2] = bf16_of(w2); b[3] = bf16_of(w3);
    b[4] = bf16_of(w4); b[5] = bf16_of(w5); b[6] = bf16_of(w6); b[7] = bf16_of(w7);
    return b;
}

// out[b][o] += x[b][kchunk] . W[o][kchunk],  W = mu + rand*softplus(rho)
// out is f32, pre-zeroed; 16 K-split partials accumulate via f32 atomics.
__global__ __launch_bounds__(256, 2) void bayes_gemm(
    const float* __restrict__ x,
    const float* __restrict__ Wmu,
    const float* __restrict__ Wrho,
    const float* __restrict__ Wrnd,
    float* __restrict__ out)
{
    const int tid  = threadIdx.x;
    const int wave = tid >> 6;
    const int lane = tid & 63;
    const int nl   = lane & 15;      // MFMA B-col / D-col index
    const int kg   = lane >> 4;      // k-group 0..3 (8 consecutive k each)

    const int o     = blockIdx.x * COLS_PER_BLOCK + wave * 16 + nl; // output col (W row)
    const int kBase = blockIdx.y * KC;

    const size_t woff = (size_t)o * IN_F + kBase + kg * 8;
    const float* pmu  = Wmu  + woff;
    const float* prho = Wrho + woff;
    const float* prnd = Wrnd + woff;
    // x rows nl, nl+16, nl+32, nl+48 ; same k window
    const float* px   = x + (size_t)nl * IN_F + kBase + kg * 8;

    f32x4 acc0 = {0.f,0.f,0.f,0.f};
    f32x4 acc1 = {0.f,0.f,0.f,0.f};
    f32x4 acc2 = {0.f,0.f,0.f,0.f};
    f32x4 acc3 = {0.f,0.f,0.f,0.f};

    #pragma unroll 2
    for (int kk = 0; kk < KC; kk += 32) {
        // ---- B fragment: 8 consecutive weights of row o ----
        const float4 mu0 = *(const float4*)(pmu);
        const float4 mu1 = *(const float4*)(pmu + 4);
        const float4 rh0 = *(const float4*)(prho);
        const float4 rh1 = *(const float4*)(prho + 4);
        const float4 rn0 = *(const float4*)(prnd);
        const float4 rn1 = *(const float4*)(prnd + 4);

        const bf16x8 bfrag = pack8(
            fmaf(rn0.x, softplus_f(rh0.x), mu0.x),
            fmaf(rn0.y, softplus_f(rh0.y), mu0.y),
            fmaf(rn0.z, softplus_f(rh0.z), mu0.z),
            fmaf(rn0.w, softplus_f(rh0.w), mu0.w),
            fmaf(rn1.x, softplus_f(rh1.x), mu1.x),
            fmaf(rn1.y, softplus_f(rh1.y), mu1.y),
            fmaf(rn1.z, softplus_f(rh1.z), mu1.z),
            fmaf(rn1.w, softplus_f(rh1.w), mu1.w));

        // ---- A fragments: x rows (mt*16 + nl), 8 consecutive k ----
        const float4 xa0 = *(const float4*)(px);
        const float4 xa1 = *(const float4*)(px + 4);
        const float4 xb0 = *(const float4*)(px + 16 * IN_F);
        const float4 xb1 = *(const float4*)(px + 16 * IN_F + 4);
        const float4 xc0 = *(const float4*)(px + 32 * IN_F);
        const float4 xc1 = *(const float4*)(px + 32 * IN_F + 4);
        const float4 xd0 = *(const float4*)(px + 48 * IN_F);
        const float4 xd1 = *(const float4*)(px + 48 * IN_F + 4);

        const bf16x8 a0 = pack8(xa0.x, xa0.y, xa0.z, xa0.w, xa1.x, xa1.y, xa1.z, xa1.w);
        const bf16x8 a1 = pack8(xb0.x, xb0.y, xb0.z, xb0.w, xb1.x, xb1.y, xb1.z, xb1.w);
        const bf16x8 a2 = pack8(xc0.x, xc0.y, xc0.z, xc0.w, xc1.x, xc1.y, xc1.z, xc1.w);
        const bf16x8 a3 = pack8(xd0.x, xd0.y, xd0.z, xd0.w, xd1.x, xd1.y, xd1.z, xd1.w);

        acc0 = __builtin_amdgcn_mfma_f32_16x16x32_bf16(a0, bfrag, acc0, 0, 0, 0);
        acc1 = __builtin_amdgcn_mfma_f32_16x16x32_bf16(a1, bfrag, acc1, 0, 0, 0);
        acc2 = __builtin_amdgcn_mfma_f32_16x16x32_bf16(a2, bfrag, acc2, 0, 0, 0);
        acc3 = __builtin_amdgcn_mfma_f32_16x16x32_bf16(a3, bfrag, acc3, 0, 0, 0);

        pmu += 32; prho += 32; prnd += 32; px += 32;
    }

    // D layout (m89-verified): col = lane&15 (== o, 2nd operand), row = kg*4 + r (batch, 1st operand)
    #pragma unroll
    for (int r = 0; r < 4; ++r) {
        const int mrow = kg * 4 + r;
        atomicAdd(&out[(size_t)(mrow     ) * OUT_F + o], acc0[r]);
        atomicAdd(&out[(size_t)(mrow + 16) * OUT_F + o], acc1[r]);
        atomicAdd(&out[(size_t)(mrow + 32) * OUT_F + o], acc2[r]);
        atomicAdd(&out[(size_t)(mrow + 48) * OUT_F + o], acc3[r]);
    }
}

// In-place bias add on the f32 output: out[b][o] += b_mu[o] + b_rand[o]*softplus(b_rho[o])
__global__ __launch_bounds__(256) void bayes_bias(
    float* __restrict__ out,
    const float* __restrict__ bmu,
    const float* __restrict__ brho,
    const float* __restrict__ brnd)
{
    const int i4 = (blockIdx.x * 256 + threadIdx.x) * 4;   // 0 .. BATCH*OUT_F-1, step 4
    float4 v = *(const float4*)(out + i4);
    const int o = i4 & (OUT_F - 1);                        // OUT_F multiple of 4 -> same row
    v.x += fmaf(brnd[o    ], softplus_f(brho[o    ]), bmu[o    ]);
    v.y += fmaf(brnd[o + 1], softplus_f(brho[o + 1]), bmu[o + 1]);
    v.z += fmaf(brnd[o + 2], softplus_f(brho[o + 2]), bmu[o + 2]);
    v.w += fmaf(brnd[o + 3], softplus_f(brho[o + 3]), bmu[o + 3]);
    *(float4*)(out + i4) = v;
}

extern "C" void kernel_launch(void* const* d_in, const int* in_sizes, int n_in,
                              void* d_out, int out_size, void* d_ws, size_t ws_size,
                              hipStream_t stream) {
    const float* x     = (const float*)d_in[0];
    const float* Wmu   = (const float*)d_in[1];
    const float* Wrho  = (const float*)d_in[2];
    const float* bmu   = (const float*)d_in[3];
    const float* brho  = (const float*)d_in[4];
    const float* Wrnd  = (const float*)d_in[5];
    const float* brnd  = (const float*)d_in[6];
    float* out = (float*)d_out;   // reference output dtype is float32

    // zero the f32 accumulation target (d_out is poisoned 0xAA before timed launches)
    hipMemsetAsync(out, 0, (size_t)BATCH * OUT_F * sizeof(float), stream);

    dim3 grid(OUT_F / COLS_PER_BLOCK, KSPLIT);   // 64 x 16 = 1024 blocks
    bayes_gemm<<<grid, 256, 0, stream>>>(x, Wmu, Wrho, Wrnd, out);

    bayes_bias<<<(BATCH * OUT_F) / (256 * 4), 256, 0, stream>>>(out, bmu, brho, brnd);
}

// Round 3
// 222.958 us; speedup vs baseline: 1.0003x; 1.0003x over previous
//
#include <hip/hip_runtime.h>
#include <hip/hip_bf16.h>

#define IN_F   4096
#define OUT_F  4096
#define BATCH  64
#define NWAVE  8                    // K-split waves per block
#define NITER  (IN_F / (NWAVE*32))  // 16 iters of 32-k, interleaved across waves

typedef __attribute__((ext_vector_type(8))) short  bf16x8;
typedef __attribute__((ext_vector_type(4))) float  f32x4;

__device__ __forceinline__ float softplus_f(float r) {
    // log(1+e^r) = max(r,0) + log(1+e^-|r|)
    return fmaxf(r, 0.0f) + __logf(1.0f + __expf(-fabsf(r)));
}

__device__ __forceinline__ short bf16_of(float f) {
    union { float f; unsigned u; } v; v.f = f;
    unsigned r = v.u + 0x7FFFu + ((v.u >> 16) & 1u);
    return (short)(r >> 16);
}

__device__ __forceinline__ bf16x8 pack8(float w0, float w1, float w2, float w3,
                                        float w4, float w5, float w6, float w7) {
    bf16x8 b;
    b[0] = bf16_of(w0); b[1] = bf16_of(w1); b[2] = bf16_of(w2); b[3] = bf16_of(w3);
    b[4] = bf16_of(w4); b[5] = bf16_of(w5); b[6] = bf16_of(w6); b[7] = bf16_of(w7);
    return b;
}

#define LD4(p) (*(const float4*)(p))

// One block = 512 threads = 8 waves, owns 16 output cols; waves split K 8-way.
// W = mu + rand*softplus(rho) built in registers, bf16 MFMA, LDS-reduce, fused bias.
__global__ __launch_bounds__(512, 2) void bayes_fused(
    const float* __restrict__ x,
    const float* __restrict__ Wmu,
    const float* __restrict__ Wrho,
    const float* __restrict__ Wrnd,
    const float* __restrict__ bmu,
    const float* __restrict__ brho,
    const float* __restrict__ brnd,
    float* __restrict__ out)
{
    __shared__ float red[NWAVE][BATCH][17];   // +1 pad: kills 4-way store conflict

    const int tid  = threadIdx.x;
    const int wave = tid >> 6;       // 0..7 = K-chunk id
    const int lane = tid & 63;
    const int nl   = lane & 15;      // MFMA B-col / D-col
    const int kg   = lane >> 4;      // k-group 0..3 (8 consecutive k)

    const int colbase = blockIdx.x * 16;
    const int o  = colbase + nl;                 // W row / output col
    const int k0 = wave * 32 + kg * 8;           // interleaved: wave strides 32, step 256

    const float* pmu  = Wmu  + (size_t)o * IN_F + k0;
    const float* prho = Wrho + (size_t)o * IN_F + k0;
    const float* prnd = Wrnd + (size_t)o * IN_F + k0;
    const float* px   = x    + (size_t)nl * IN_F + k0;

    f32x4 acc0 = {0.f,0.f,0.f,0.f};
    f32x4 acc1 = {0.f,0.f,0.f,0.f};
    f32x4 acc2 = {0.f,0.f,0.f,0.f};
    f32x4 acc3 = {0.f,0.f,0.f,0.f};

    // ---- prologue: load iter 0 ----
    float4 cm0 = LD4(pmu),      cm1 = LD4(pmu + 4);
    float4 cr0 = LD4(prho),     cr1 = LD4(prho + 4);
    float4 cn0 = LD4(prnd),     cn1 = LD4(prnd + 4);
    float4 xA0 = LD4(px),                xA1 = LD4(px + 4);
    float4 xB0 = LD4(px + 16*IN_F),      xB1 = LD4(px + 16*IN_F + 4);
    float4 xC0 = LD4(px + 32*IN_F),      xC1 = LD4(px + 32*IN_F + 4);
    float4 xD0 = LD4(px + 48*IN_F),      xD1 = LD4(px + 48*IN_F + 4);

    #pragma unroll
    for (int it = 0; it < NITER; ++it) {
        pmu += NWAVE*32; prho += NWAVE*32; prnd += NWAVE*32; px += NWAVE*32;

        // ---- prefetch iter it+1 FIRST (independent of current compute) ----
        float4 nm0 = cm0, nm1 = cm1, nr0 = cr0, nr1 = cr1, nn0 = cn0, nn1 = cn1;
        float4 yA0 = xA0, yA1 = xA1, yB0 = xB0, yB1 = xB1;
        float4 yC0 = xC0, yC1 = xC1, yD0 = xD0, yD1 = xD1;
        if (it + 1 < NITER) {
            nm0 = LD4(pmu);      nm1 = LD4(pmu + 4);
            nr0 = LD4(prho);     nr1 = LD4(prho + 4);
            nn0 = LD4(prnd);     nn1 = LD4(prnd + 4);
            yA0 = LD4(px);               yA1 = LD4(px + 4);
            yB0 = LD4(px + 16*IN_F);     yB1 = LD4(px + 16*IN_F + 4);
            yC0 = LD4(px + 32*IN_F);     yC1 = LD4(px + 32*IN_F + 4);
            yD0 = LD4(px + 48*IN_F);     yD1 = LD4(px + 48*IN_F + 4);
        }

        // ---- B fragment: W = mu + rnd*softplus(rho), 8 consecutive k of row o ----
        const bf16x8 bfrag = pack8(
            fmaf(cn0.x, softplus_f(cr0.x), cm0.x),
            fmaf(cn0.y, softplus_f(cr0.y), cm0.y),
            fmaf(cn0.z, softplus_f(cr0.z), cm0.z),
            fmaf(cn0.w, softplus_f(cr0.w), cm0.w),
            fmaf(cn1.x, softplus_f(cr1.x), cm1.x),
            fmaf(cn1.y, softplus_f(cr1.y), cm1.y),
            fmaf(cn1.z, softplus_f(cr1.z), cm1.z),
            fmaf(cn1.w, softplus_f(cr1.w), cm1.w));

        // ---- A fragments: x rows nl, nl+16, nl+32, nl+48 ----
        const bf16x8 a0 = pack8(xA0.x,xA0.y,xA0.z,xA0.w, xA1.x,xA1.y,xA1.z,xA1.w);
        const bf16x8 a1 = pack8(xB0.x,xB0.y,xB0.z,xB0.w, xB1.x,xB1.y,xB1.z,xB1.w);
        const bf16x8 a2 = pack8(xC0.x,xC0.y,xC0.z,xC0.w, xC1.x,xC1.y,xC1.z,xC1.w);
        const bf16x8 a3 = pack8(xD0.x,xD0.y,xD0.z,xD0.w, xD1.x,xD1.y,xD1.z,xD1.w);

        acc0 = __builtin_amdgcn_mfma_f32_16x16x32_bf16(a0, bfrag, acc0, 0, 0, 0);
        acc1 = __builtin_amdgcn_mfma_f32_16x16x32_bf16(a1, bfrag, acc1, 0, 0, 0);
        acc2 = __builtin_amdgcn_mfma_f32_16x16x32_bf16(a2, bfrag, acc2, 0, 0, 0);
        acc3 = __builtin_amdgcn_mfma_f32_16x16x32_bf16(a3, bfrag, acc3, 0, 0, 0);

        // rotate
        cm0=nm0; cm1=nm1; cr0=nr0; cr1=nr1; cn0=nn0; cn1=nn1;
        xA0=yA0; xA1=yA1; xB0=yB0; xB1=yB1; xC0=yC0; xC1=yC1; xD0=yD0; xD1=yD1;
    }

    // ---- per-wave partials -> LDS.  D layout: batch = a*16 + kg*4 + r, col = nl ----
    #pragma unroll
    for (int r = 0; r < 4; ++r) {
        red[wave][ 0 + kg*4 + r][nl] = acc0[r];
        red[wave][16 + kg*4 + r][nl] = acc1[r];
        red[wave][32 + kg*4 + r][nl] = acc2[r];
        red[wave][48 + kg*4 + r][nl] = acc3[r];
    }
    __syncthreads();

    // ---- reduce 8 partials + bias, store f32 (each of 1024 outputs once) ----
    #pragma unroll
    for (int e = tid; e < BATCH*16; e += 512) {
        const int b = e >> 4;
        const int c = e & 15;
        float s = 0.f;
        #pragma unroll
        for (int w = 0; w < NWAVE; ++w) s += red[w][b][c];
        const int oc = colbase + c;
        s += fmaf(brnd[oc], softplus_f(brho[oc]), bmu[oc]);
        out[(size_t)b * OUT_F + oc] = s;
    }
}

extern "C" void kernel_launch(void* const* d_in, const int* in_sizes, int n_in,
                              void* d_out, int out_size, void* d_ws, size_t ws_size,
                              hipStream_t stream) {
    const float* x     = (const float*)d_in[0];
    const float* Wmu   = (const float*)d_in[1];
    const float* Wrho  = (const float*)d_in[2];
    const float* bmu   = (const float*)d_in[3];
    const float* brho  = (const float*)d_in[4];
    const float* Wrnd  = (const float*)d_in[5];
    const float* brnd  = (const float*)d_in[6];
    float* out = (float*)d_out;   // reference output dtype is float32

    bayes_fused<<<OUT_F/16, 512, 0, stream>>>(x, Wmu, Wrho, Wrnd, bmu, brho, brnd, out);
}